// Round 15
// baseline (98.350 us; speedup 1.0000x reference)
//
#include <hip/hip_runtime.h>
#include <float.h>
#include <math.h>

#define B_N 8
#define C_N 256
#define L_N 8192
#define A_N 128
#define LT 64
#define NTILES (L_N / LT)   // 128 tiles per batch

typedef short bf16x8 __attribute__((ext_vector_type(8)));
typedef float f32x4 __attribute__((ext_vector_type(4)));

__device__ __forceinline__ short f2bf(float f) {
  union { float f; unsigned u; } v; v.f = f;
  unsigned r = v.u + 0x7fffu + ((v.u >> 16) & 1u);
  return (short)(r >> 16);
}

__device__ __forceinline__ unsigned cvt_pk_bf16(float lo, float hi) {
  unsigned r;
  asm("v_cvt_pk_bf16_f32 %0, %1, %2" : "=v"(r) : "v"(lo), "v"(hi));
  return r;
}

// ---------------- Kernel A: stats (blocks 0..2047) + weight convert (blocks 2048..2303) ----------
__global__ __launch_bounds__(128)
void kA_stats_convert(const float* __restrict__ x, const float* __restrict__ lengths,
                      const float* __restrict__ w_val, const float* __restrict__ w_tdnn,
                      const float* __restrict__ w_conv,
                      float* __restrict__ gmean, float* __restrict__ gstd,
                      short* __restrict__ wv, short* __restrict__ wt, short* __restrict__ wc) {
  if (blockIdx.x < 2048) {
    __shared__ float sm[2][3];
    int blk = blockIdx.x;              // b*256 + c
    int b = blk >> 8;
    int wave = threadIdx.x >> 6;
    int lane = threadIdx.x & 63;
    float vlen = lengths[b] * (float)L_N;
    const float4* row = (const float4*)(x + (size_t)blk * L_N + wave * (L_N / 2));
    float s = 0.f, s2 = 0.f, cnt = 0.f;
    if (wave == 0) {
#pragma unroll 4
      for (int i = lane; i < 1024; i += 64) {
        float4 q = row[i];
        s += q.x + q.y + q.z + q.w;
        s2 += q.x * q.x + q.y * q.y + q.z * q.z + q.w * q.w;
      }
      cnt = 64.f;
    } else {
      for (int i = lane; i < 1024; i += 64) {
        int l = 4096 + i * 4;
        if ((float)l >= vlen) break;
        float4 q = row[i];
        if ((float)(l + 3) < vlen) {
          s += q.x + q.y + q.z + q.w;
          s2 += q.x * q.x + q.y * q.y + q.z * q.z + q.w * q.w;
          cnt += 4.f;
        } else {
          float e[4] = {q.x, q.y, q.z, q.w};
#pragma unroll
          for (int j = 0; j < 4; ++j) {
            if ((float)(l + j) < vlen) { float t = e[j]; s += t; s2 += t * t; cnt += 1.f; }
          }
        }
      }
    }
#pragma unroll
    for (int off = 32; off; off >>= 1) {
      s += __shfl_xor(s, off); s2 += __shfl_xor(s2, off); cnt += __shfl_xor(cnt, off);
    }
    if (lane == 0) { sm[wave][0] = s; sm[wave][1] = s2; sm[wave][2] = cnt; }
    __syncthreads();
    if (threadIdx.x == 0) {
      float S = sm[0][0] + sm[1][0];
      float S2 = sm[0][1] + sm[1][1];
      float CNT = sm[0][2] + sm[1][2];
      float mean = S / CNT;
      float var = S2 / CNT - mean * mean;
      gmean[blk] = mean;
      gstd[blk] = sqrtf(fmaxf(var, 1e-12f));
    }
  } else {
    int unit = (blockIdx.x - 2048) * 2 + (threadIdx.x >> 6);   // 0..511
    int lane = threadIdx.x & 63;
    int t = unit * 64 + lane;            // 0..32767
    const float* src;
    short* dst;
    int p, c, k, rowlen;
    if (t < 16384) {                     // wv: [16 colblk][8 kblk]
      p = t * 4;
      int j0 = p & 7, lane_ = (p >> 3) & 63, bi = p >> 9;
      int kblk = bi & 7, colblk = bi >> 3;
      c = colblk * 16 + (lane_ & 15);
      k = kblk * 32 + (lane_ >> 4) * 8 + j0;
      src = w_val; dst = wv; rowlen = 768;
    } else if (t < 24576) {              // wt: [8 colblk][8 kblk]
      p = (t - 16384) * 4;
      int j0 = p & 7, lane_ = (p >> 3) & 63, bi = p >> 9;
      int kblk = bi & 7, colblk = bi >> 3;
      c = colblk * 16 + (lane_ & 15);
      k = kblk * 32 + (lane_ >> 4) * 8 + j0;
      src = w_tdnn; dst = wt; rowlen = 768;
    } else {                             // wc: [16 colblk][4 kblk]
      p = (t - 24576) * 4;
      int j0 = p & 7, lane_ = (p >> 3) & 63, bi = p >> 9;
      int kblk = bi & 3, colblk = bi >> 2;
      c = colblk * 16 + (lane_ & 15);
      k = kblk * 32 + (lane_ >> 4) * 8 + j0;
      src = w_conv; dst = wc; rowlen = 128;
    }
    float4 q = *(const float4*)(src + (size_t)c * rowlen + k);
    short4 o = make_short4(f2bf(q.x), f2bf(q.y), f2bf(q.z), f2bf(q.w));
    *(short4*)(dst + p) = o;
  }
}

// ---------------- Kernel B: fp32 bias GEMVs (needs stats) ----------------
__global__ __launch_bounds__(256)
void kB_bias(const float* __restrict__ w_val, const float* __restrict__ b_val,
             const float* __restrict__ w_tdnn, const float* __restrict__ b_tdnn,
             const float* __restrict__ gmean, const float* __restrict__ gstd,
             float* __restrict__ bias_val, float* __restrict__ hbias) {
  int unit = blockIdx.x * 4 + (threadIdx.x >> 6);   // 0..3071
  int lane = threadIdx.x & 63;
  if (unit < 2048) {                      // bias_val[b][c]
    int b = unit >> 8, c = unit & 255;
    const float* wr = w_val + c * 768;
    const float* gm = gmean + b * 256;
    const float* gs = gstd + b * 256;
    float s = 0.f;
    for (int j = lane; j < 256; j += 64)
      s += gm[j] * wr[256 + j] + gs[j] * wr[512 + j];
#pragma unroll
    for (int off = 32; off; off >>= 1) s += __shfl_xor(s, off);
    if (lane == 0) bias_val[b * 256 + c] = s + b_val[c];
  } else {                                // hbias[b][a]
    int t = unit - 2048;
    int b = t >> 7, a = t & 127;
    const float* wr = w_tdnn + a * 768;
    const float* gm = gmean + b * 256;
    const float* gs = gstd + b * 256;
    float s = 0.f;
    for (int j = lane; j < 256; j += 64)
      s += gm[j] * wr[256 + j] + gs[j] * wr[512 + j];
#pragma unroll
    for (int off = 32; off; off >>= 1) s += __shfl_xor(s, off);
    if (lane == 0) hbias[b * 128 + a] = s + b_tdnn[a];
  }
}

// ---------------- K3: verified 8-wave, TWO tiles per block with hidden stage(t1) ------
__global__ __launch_bounds__(512, 4)
void k3_main8w(const float* __restrict__ x, const float* __restrict__ lengths,
               const short* __restrict__ wv, const short* __restrict__ wt,
               const short* __restrict__ wc,
               const float* __restrict__ bias_val, const float* __restrict__ hbias,
               const float* __restrict__ bn_gamma, const float* __restrict__ bn_beta,
               const float* __restrict__ b_conv,
               float4* __restrict__ partial) {
  __shared__ short xs[LT][C_N + 8];   // x tile [l][c'] bf16
  __shared__ short hs[LT][A_N + 8];   // h tile [l][a] bf16

  int blk = blockIdx.x;    // 0..511
  int b = blk >> 6;
  int t0 = (blk & 63) * 2;
  int tid = threadIdx.x;
  int wave = tid >> 6;     // 0..7
  int lane = tid & 63;
  int lr = lane & 15;
  int lg = lane >> 4;
  int lgrp = tid & 15;     // staging l-group
  int crow = tid >> 4;     // staging c-row 0..31

  float vlen = lengths[b] * (float)L_N;

  // ---- fully-invalid pair: t0 invalid => t1 invalid ----
  if ((float)(t0 * LT) >= vlen) {
    if (lg == 0) {
#pragma unroll
      for (int nt = 0; nt < 2; ++nt) {
        int c = wave * 32 + nt * 16 + lr;
        partial[(size_t)((b * NTILES + t0) * C_N) + c]     = make_float4(-FLT_MAX, 0.f, 0.f, 0.f);
        partial[(size_t)((b * NTILES + t0 + 1) * C_N) + c] = make_float4(-FLT_MAX, 0.f, 0.f, 0.f);
      }
    }
    return;
  }
  bool t1_valid = (float)((t0 + 1) * LT) < vlen;

  // ---- per-block epilogue constants (shared by both tiles) ----
  int ai = wave * 16 + lr;
  float hb = hbias[b * A_N + ai];
  float g  = bn_gamma[ai];
  float be = bn_beta[ai];
  float bc2[2], bv2[2];
#pragma unroll
  for (int nt = 0; nt < 2; ++nt) {
    int c = wave * 32 + nt * 16 + lr;
    bc2[nt] = b_conv[c];
    bv2[nt] = bias_val[b * C_N + c];
  }

  // ---- stage tile t0 into xs ----
  {
    const float* xb = x + (size_t)b * C_N * L_N + t0 * LT + lgrp * 4;
#pragma unroll
    for (int i = 0; i < 2; ++i) {
      int c0 = (i * 32 + crow) * 4;
      float4 q0 = *(const float4*)(xb + (size_t)(c0 + 0) * L_N);
      float4 q1 = *(const float4*)(xb + (size_t)(c0 + 1) * L_N);
      float4 q2 = *(const float4*)(xb + (size_t)(c0 + 2) * L_N);
      float4 q3 = *(const float4*)(xb + (size_t)(c0 + 3) * L_N);
      float e0[4] = {q0.x, q0.y, q0.z, q0.w};
      float e1[4] = {q1.x, q1.y, q1.z, q1.w};
      float e2[4] = {q2.x, q2.y, q2.z, q2.w};
      float e3[4] = {q3.x, q3.y, q3.z, q3.w};
#pragma unroll
      for (int r = 0; r < 4; ++r) {
        unsigned u0 = cvt_pk_bf16(e0[r], e1[r]);
        unsigned u1 = cvt_pk_bf16(e2[r], e3[r]);
        *(uint2*)&xs[lgrp * 4 + r][c0] = make_uint2(u0, u1);
      }
    }
  }
  __syncthreads();

  f32x4 zero4 = {0.f, 0.f, 0.f, 0.f};

#pragma unroll 1
  for (int ti = 0; ti < 2; ++ti) {
    int tile = t0 + ti;
    int l0 = tile * LT;

    // ---- V (values) + Hpre GEMMs over xs ----
    f32x4 accv[4][2];
    f32x4 acch[4];
#pragma unroll
    for (int mt = 0; mt < 4; ++mt) {
#pragma unroll
      for (int nt = 0; nt < 2; ++nt) accv[mt][nt] = zero4;
      acch[mt] = zero4;
    }

    for (int k0 = 0; k0 < C_N; k0 += 32) {
      int kb = k0 >> 5;
      bf16x8 af[4];
#pragma unroll
      for (int mt = 0; mt < 4; ++mt)
        af[mt] = *(const bf16x8*)&xs[mt * 16 + lr][k0 + lg * 8];
#pragma unroll
      for (int nt = 0; nt < 2; ++nt) {
        const bf16x8 bf = *(const bf16x8*)&wv[(((wave * 2 + nt) * 8 + kb) * 64 + lane) * 8];
#pragma unroll
        for (int mt = 0; mt < 4; ++mt)
          accv[mt][nt] = __builtin_amdgcn_mfma_f32_16x16x32_bf16(af[mt], bf, accv[mt][nt], 0, 0, 0);
      }
      {
        const bf16x8 bf = *(const bf16x8*)&wt[((wave * 8 + kb) * 64 + lane) * 8];
#pragma unroll
        for (int mt = 0; mt < 4; ++mt)
          acch[mt] = __builtin_amdgcn_mfma_f32_16x16x32_bf16(af[mt], bf, acch[mt], 0, 0, 0);
      }
    }
    __builtin_amdgcn_sched_barrier(0);

    // ---- prefetch next tile's x into regs (hidden under epilogue+GEMM2) ----
    bool pf = (ti == 0) && t1_valid;
    float4 q[8];
    if (pf) {
      const float* xb = x + (size_t)b * C_N * L_N + (t0 + 1) * LT + lgrp * 4;
#pragma unroll
      for (int i = 0; i < 2; ++i)
#pragma unroll
        for (int j = 0; j < 4; ++j)
          q[i * 4 + j] = *(const float4*)(xb + (size_t)((i * 32 + crow) * 4 + j) * L_N);
    }

    // ---- h epilogue: relu + BN affine -> hs ----
#pragma unroll
    for (int mt = 0; mt < 4; ++mt) {
#pragma unroll
      for (int r = 0; r < 4; ++r) {
        float hv = acch[mt][r] + hb;
        hv = fmaxf(hv, 0.f) * g + be;
        hs[mt * 16 + lg * 4 + r][ai] = f2bf(hv);
      }
    }
    __syncthreads();

    // ---- S (scores) GEMM over hs ----
    f32x4 accs[4][2];
#pragma unroll
    for (int mt = 0; mt < 4; ++mt)
#pragma unroll
      for (int nt = 0; nt < 2; ++nt) accs[mt][nt] = zero4;

    for (int k0 = 0; k0 < A_N; k0 += 32) {
      int kb = k0 >> 5;
      bf16x8 af[4];
#pragma unroll
      for (int mt = 0; mt < 4; ++mt)
        af[mt] = *(const bf16x8*)&hs[mt * 16 + lr][k0 + lg * 8];
#pragma unroll
      for (int nt = 0; nt < 2; ++nt) {
        const bf16x8 bf = *(const bf16x8*)&wc[(((wave * 2 + nt) * 4 + kb) * 64 + lane) * 8];
#pragma unroll
        for (int mt = 0; mt < 4; ++mt)
          accs[mt][nt] = __builtin_amdgcn_mfma_f32_16x16x32_bf16(af[mt], bf, accs[mt][nt], 0, 0, 0);
      }
    }
    __builtin_amdgcn_sched_barrier(0);

    // ---- per-tile online-softmax partials ----
    bool fullvalid = (float)(l0 + LT - 1) < vlen;

#pragma unroll
    for (int nt = 0; nt < 2; ++nt) {
      int c = wave * 32 + nt * 16 + lr;
      float bc = bc2[nt];
      float bv = bv2[nt];
      float m = -FLT_MAX, ss = 0.f, sv = 0.f, svv = 0.f;
      if (fullvalid) {
#pragma unroll
        for (int mt = 0; mt < 4; ++mt)
#pragma unroll
          for (int r = 0; r < 4; ++r) m = fmaxf(m, accs[mt][nt][r]);
        m = fmaxf(m, __shfl_xor(m, 16));
        m = fmaxf(m, __shfl_xor(m, 32));
#pragma unroll
        for (int mt = 0; mt < 4; ++mt) {
#pragma unroll
          for (int r = 0; r < 4; ++r) {
            float p = __expf(accs[mt][nt][r] - m);
            float v = accv[mt][nt][r] + bv;
            ss += p; sv += p * v; svv += p * v * v;
          }
        }
      } else {
        float lbase = (float)(l0 + lg * 4);
#pragma unroll
        for (int mt = 0; mt < 4; ++mt)
#pragma unroll
          for (int r = 0; r < 4; ++r) {
            bool valid = (lbase + (float)(mt * 16 + r)) < vlen;
            m = fmaxf(m, valid ? accs[mt][nt][r] : -FLT_MAX);
          }
        m = fmaxf(m, __shfl_xor(m, 16));
        m = fmaxf(m, __shfl_xor(m, 32));
#pragma unroll
        for (int mt = 0; mt < 4; ++mt) {
#pragma unroll
          for (int r = 0; r < 4; ++r) {
            bool valid = (lbase + (float)(mt * 16 + r)) < vlen;
            float p = valid ? __expf(accs[mt][nt][r] - m) : 0.f;
            float v = accv[mt][nt][r] + bv;
            ss += p; sv += p * v; svv += p * v * v;
          }
        }
      }
      m += bc;
      ss += __shfl_xor(ss, 16); ss += __shfl_xor(ss, 32);
      sv += __shfl_xor(sv, 16); sv += __shfl_xor(sv, 32);
      svv += __shfl_xor(svv, 16); svv += __shfl_xor(svv, 32);
      if (lg == 0) {
        partial[(size_t)((b * NTILES + tile) * C_N) + c] = make_float4(m, ss, sv, svv);
      }
    }

    if (ti == 0) {
      if (!t1_valid) {
        // t1 fully invalid: defaults and done
        if (lg == 0) {
#pragma unroll
          for (int nt = 0; nt < 2; ++nt) {
            int c = wave * 32 + nt * 16 + lr;
            partial[(size_t)((b * NTILES + t0 + 1) * C_N) + c] = make_float4(-FLT_MAX, 0.f, 0.f, 0.f);
          }
        }
        return;
      }
      // write prefetched t1 into xs (xs unread since GEMM1; hs readers unaffected)
#pragma unroll
      for (int i = 0; i < 2; ++i) {
        int c0 = (i * 32 + crow) * 4;
        float e0[4] = {q[i*4+0].x, q[i*4+0].y, q[i*4+0].z, q[i*4+0].w};
        float e1[4] = {q[i*4+1].x, q[i*4+1].y, q[i*4+1].z, q[i*4+1].w};
        float e2[4] = {q[i*4+2].x, q[i*4+2].y, q[i*4+2].z, q[i*4+2].w};
        float e3[4] = {q[i*4+3].x, q[i*4+3].y, q[i*4+3].z, q[i*4+3].w};
#pragma unroll
        for (int r = 0; r < 4; ++r) {
          unsigned u0 = cvt_pk_bf16(e0[r], e1[r]);
          unsigned u1 = cvt_pk_bf16(e2[r], e3[r]);
          *(uint2*)&xs[lgrp * 4 + r][c0] = make_uint2(u0, u1);
        }
      }
      __syncthreads();   // xs(t1) ready for GEMM1(t1); also orders hs reuse
    }
  }
}

// ---------------- K4: merge partials, emit amean/astd ----------------
__global__ __launch_bounds__(64)
void k4_combine(const float4* __restrict__ partial, float* __restrict__ out) {
  int blk = blockIdx.x;           // b*256 + c
  int b = blk >> 8, c = blk & 255;
  int lane = threadIdx.x;
  float m = -FLT_MAX, s = 0.f, sv = 0.f, svv = 0.f;
  for (int t = lane; t < NTILES; t += 64) {
    float4 q = partial[(size_t)((b * NTILES + t) * C_N) + c];
    float M = fmaxf(m, q.x);
    float e1 = __expf(m - M), e2 = __expf(q.x - M);
    s = s * e1 + q.y * e2;
    sv = sv * e1 + q.z * e2;
    svv = svv * e1 + q.w * e2;
    m = M;
  }
#pragma unroll
  for (int off = 32; off; off >>= 1) {
    float m2 = __shfl_xor(m, off), s2 = __shfl_xor(s, off);
    float sv2 = __shfl_xor(sv, off), svv2 = __shfl_xor(svv, off);
    float M = fmaxf(m, m2);
    float e1 = __expf(m - M), e2 = __expf(m2 - M);
    s = s * e1 + s2 * e2;
    sv = sv * e1 + sv2 * e2;
    svv = svv * e1 + svv2 * e2;
    m = M;
  }
  if (lane == 0) {
    float amean = sv / s;
    float avar = svv / s - amean * amean;
    out[b * 512 + c] = amean;
    out[b * 512 + 256 + c] = sqrtf(fmaxf(avar, 1e-12f));
  }
}

extern "C" void kernel_launch(void* const* d_in, const int* in_sizes, int n_in,
                              void* d_out, int out_size, void* d_ws, size_t ws_size,
                              hipStream_t stream) {
  const float* x        = (const float*)d_in[0];
  const float* lengths  = (const float*)d_in[1];
  const float* w_val    = (const float*)d_in[2];
  const float* b_val    = (const float*)d_in[3];
  const float* w_tdnn   = (const float*)d_in[4];
  const float* b_tdnn   = (const float*)d_in[5];
  const float* bn_gamma = (const float*)d_in[6];
  const float* bn_beta  = (const float*)d_in[7];
  const float* w_conv   = (const float*)d_in[8];
  const float* b_conv   = (const float*)d_in[9];
  float* out = (float*)d_out;

  char* ws = (char*)d_ws;
  float* gmean     = (float*)(ws + 0);            // 8 KB
  float* gstd      = (float*)(ws + 8 * 1024);     // 8 KB
  float* bias_val  = (float*)(ws + 16 * 1024);    // 8 KB
  float* hbias     = (float*)(ws + 24 * 1024);    // 4 KB
  short* wv        = (short*)(ws + 32 * 1024);    // 128 KB  packed [16cb][8kb][64][8]
  short* wt        = (short*)(ws + 160 * 1024);   // 64 KB   packed [8cb][8kb][64][8]
  short* wc        = (short*)(ws + 224 * 1024);   // 64 KB   packed [16cb][4kb][64][8]
  float4* partial  = (float4*)(ws + 512 * 1024);  // 4 MB    [8][128][256] float4

  kA_stats_convert<<<dim3(2304), dim3(128), 0, stream>>>(x, lengths, w_val, w_tdnn, w_conv,
                                                         gmean, gstd, wv, wt, wc);
  kB_bias<<<dim3(768), dim3(256), 0, stream>>>(w_val, b_val, w_tdnn, b_tdnn,
                                               gmean, gstd, bias_val, hbias);
  k3_main8w<<<dim3(B_N * NTILES / 2), dim3(512), 0, stream>>>(x, lengths, wv, wt, wc,
                                                              bias_val, hbias, bn_gamma, bn_beta,
                                                              b_conv, partial);
  k4_combine<<<dim3(B_N * C_N), dim3(64), 0, stream>>>(partial, out);
}

// Round 16
// 47.680 us; speedup vs baseline: 2.0627x; 2.0627x over previous
//
#include <hip/hip_runtime.h>
#include <float.h>
#include <math.h>

#define B_N 8
#define C_N 256
#define L_N 8192
#define A_N 128
#define LT 64
#define NTILES (L_N / LT)   // 128 tiles per batch

typedef short bf16x8 __attribute__((ext_vector_type(8)));
typedef float f32x4 __attribute__((ext_vector_type(4)));

__device__ __forceinline__ short f2bf(float f) {
  union { float f; unsigned u; } v; v.f = f;
  unsigned r = v.u + 0x7fffu + ((v.u >> 16) & 1u);
  return (short)(r >> 16);
}

__device__ __forceinline__ unsigned cvt_pk_bf16(float lo, float hi) {
  unsigned r;
  asm("v_cvt_pk_bf16_f32 %0, %1, %2" : "=v"(r) : "v"(lo), "v"(hi));
  return r;
}

// ---------------- Kernel A: stats (blocks 0..2047) + weight convert (blocks 2048..2303) ----------
__global__ __launch_bounds__(128)
void kA_stats_convert(const float* __restrict__ x, const float* __restrict__ lengths,
                      const float* __restrict__ w_val, const float* __restrict__ w_tdnn,
                      const float* __restrict__ w_conv,
                      float* __restrict__ gmean, float* __restrict__ gstd,
                      short* __restrict__ wv, short* __restrict__ wt, short* __restrict__ wc) {
  if (blockIdx.x < 2048) {
    __shared__ float sm[2][3];
    int blk = blockIdx.x;              // b*256 + c
    int b = blk >> 8;
    int wave = threadIdx.x >> 6;
    int lane = threadIdx.x & 63;
    float vlen = lengths[b] * (float)L_N;
    const float4* row = (const float4*)(x + (size_t)blk * L_N + wave * (L_N / 2));
    float s = 0.f, s2 = 0.f, cnt = 0.f;
    if (wave == 0) {
#pragma unroll 4
      for (int i = lane; i < 1024; i += 64) {
        float4 q = row[i];
        s += q.x + q.y + q.z + q.w;
        s2 += q.x * q.x + q.y * q.y + q.z * q.z + q.w * q.w;
      }
      cnt = 64.f;
    } else {
      for (int i = lane; i < 1024; i += 64) {
        int l = 4096 + i * 4;
        if ((float)l >= vlen) break;
        float4 q = row[i];
        if ((float)(l + 3) < vlen) {
          s += q.x + q.y + q.z + q.w;
          s2 += q.x * q.x + q.y * q.y + q.z * q.z + q.w * q.w;
          cnt += 4.f;
        } else {
          float e[4] = {q.x, q.y, q.z, q.w};
#pragma unroll
          for (int j = 0; j < 4; ++j) {
            if ((float)(l + j) < vlen) { float t = e[j]; s += t; s2 += t * t; cnt += 1.f; }
          }
        }
      }
    }
#pragma unroll
    for (int off = 32; off; off >>= 1) {
      s += __shfl_xor(s, off); s2 += __shfl_xor(s2, off); cnt += __shfl_xor(cnt, off);
    }
    if (lane == 0) { sm[wave][0] = s; sm[wave][1] = s2; sm[wave][2] = cnt; }
    __syncthreads();
    if (threadIdx.x == 0) {
      float S = sm[0][0] + sm[1][0];
      float S2 = sm[0][1] + sm[1][1];
      float CNT = sm[0][2] + sm[1][2];
      float mean = S / CNT;
      float var = S2 / CNT - mean * mean;
      gmean[blk] = mean;
      gstd[blk] = sqrtf(fmaxf(var, 1e-12f));
    }
  } else {
    int unit = (blockIdx.x - 2048) * 2 + (threadIdx.x >> 6);   // 0..511
    int lane = threadIdx.x & 63;
    int t = unit * 64 + lane;            // 0..32767
    const float* src;
    short* dst;
    int p, c, k, rowlen;
    if (t < 16384) {                     // wv: [16 colblk][8 kblk]
      p = t * 4;
      int j0 = p & 7, lane_ = (p >> 3) & 63, bi = p >> 9;
      int kblk = bi & 7, colblk = bi >> 3;
      c = colblk * 16 + (lane_ & 15);
      k = kblk * 32 + (lane_ >> 4) * 8 + j0;
      src = w_val; dst = wv; rowlen = 768;
    } else if (t < 24576) {              // wt: [8 colblk][8 kblk]
      p = (t - 16384) * 4;
      int j0 = p & 7, lane_ = (p >> 3) & 63, bi = p >> 9;
      int kblk = bi & 7, colblk = bi >> 3;
      c = colblk * 16 + (lane_ & 15);
      k = kblk * 32 + (lane_ >> 4) * 8 + j0;
      src = w_tdnn; dst = wt; rowlen = 768;
    } else {                             // wc: [16 colblk][4 kblk]
      p = (t - 24576) * 4;
      int j0 = p & 7, lane_ = (p >> 3) & 63, bi = p >> 9;
      int kblk = bi & 3, colblk = bi >> 2;
      c = colblk * 16 + (lane_ & 15);
      k = kblk * 32 + (lane_ >> 4) * 8 + j0;
      src = w_conv; dst = wc; rowlen = 128;
    }
    float4 q = *(const float4*)(src + (size_t)c * rowlen + k);
    short4 o = make_short4(f2bf(q.x), f2bf(q.y), f2bf(q.z), f2bf(q.w));
    *(short4*)(dst + p) = o;
  }
}

// ---------------- Kernel B: fp32 bias GEMVs (needs stats) ----------------
__global__ __launch_bounds__(256)
void kB_bias(const float* __restrict__ w_val, const float* __restrict__ b_val,
             const float* __restrict__ w_tdnn, const float* __restrict__ b_tdnn,
             const float* __restrict__ gmean, const float* __restrict__ gstd,
             float* __restrict__ bias_val, float* __restrict__ hbias) {
  int unit = blockIdx.x * 4 + (threadIdx.x >> 6);   // 0..3071
  int lane = threadIdx.x & 63;
  if (unit < 2048) {                      // bias_val[b][c]
    int b = unit >> 8, c = unit & 255;
    const float* wr = w_val + c * 768;
    const float* gm = gmean + b * 256;
    const float* gs = gstd + b * 256;
    float s = 0.f;
    for (int j = lane; j < 256; j += 64)
      s += gm[j] * wr[256 + j] + gs[j] * wr[512 + j];
#pragma unroll
    for (int off = 32; off; off >>= 1) s += __shfl_xor(s, off);
    if (lane == 0) bias_val[b * 256 + c] = s + b_val[c];
  } else {                                // hbias[b][a]
    int t = unit - 2048;
    int b = t >> 7, a = t & 127;
    const float* wr = w_tdnn + a * 768;
    const float* gm = gmean + b * 256;
    const float* gs = gstd + b * 256;
    float s = 0.f;
    for (int j = lane; j < 256; j += 64)
      s += gm[j] * wr[256 + j] + gs[j] * wr[512 + j];
#pragma unroll
    for (int off = 32; off; off >>= 1) s += __shfl_xor(s, off);
    if (lane == 0) hbias[b * 128 + a] = s + b_tdnn[a];
  }
}

// ---------------- K3 (R13 proven): verified 8-wave + invalid-tile early exit ----------------
__global__ __launch_bounds__(512, 4)
void k3_main8w(const float* __restrict__ x, const float* __restrict__ lengths,
               const short* __restrict__ wv, const short* __restrict__ wt,
               const short* __restrict__ wc,
               const float* __restrict__ bias_val, const float* __restrict__ hbias,
               const float* __restrict__ bn_gamma, const float* __restrict__ bn_beta,
               const float* __restrict__ b_conv,
               float4* __restrict__ partial) {
  __shared__ short xs[LT][C_N + 8];   // x tile [l][c'] bf16
  __shared__ short hs[LT][A_N + 8];   // h tile [l][a] bf16

  int blk = blockIdx.x;
  int b = blk >> 7;
  int tile = blk & 127;
  int l0 = tile * LT;
  int tid = threadIdx.x;
  int wave = tid >> 6;     // 0..7
  int lane = tid & 63;
  int lr = lane & 15;
  int lg = lane >> 4;

  float vlen = lengths[b] * (float)L_N;

  // ---- fully-invalid tile: partials are exactly (-inf,0,0,0); skip all compute ----
  if ((float)l0 >= vlen) {
    if (lg == 0) {
#pragma unroll
      for (int nt = 0; nt < 2; ++nt) {
        int c = wave * 32 + nt * 16 + lr;
        partial[(size_t)((b * NTILES + tile) * C_N) + c] = make_float4(-FLT_MAX, 0.f, 0.f, 0.f);
      }
    }
    return;
  }

  // ---- prefetch per-thread epilogue constants ----
  int ai = wave * 16 + lr;               // h col this thread handles
  float hb = hbias[b * A_N + ai];
  float g  = bn_gamma[ai];
  float be = bn_beta[ai];
  float bc2[2], bv2[2];
#pragma unroll
  for (int nt = 0; nt < 2; ++nt) {
    int c = wave * 32 + nt * 16 + lr;
    bc2[nt] = b_conv[c];
    bv2[nt] = bias_val[b * C_N + c];
  }

  // ---- stage x tile: global [c'][l] fp32 -> LDS [l][c'] bf16 ----
  {
    int lgrp = tid & 15;
    int crow = tid >> 4;                 // 0..31
    const float* xb = x + (size_t)b * C_N * L_N + l0 + lgrp * 4;
#pragma unroll
    for (int i = 0; i < 2; ++i) {
      int c0 = (i * 32 + crow) * 4;
      float4 q0 = *(const float4*)(xb + (size_t)(c0 + 0) * L_N);
      float4 q1 = *(const float4*)(xb + (size_t)(c0 + 1) * L_N);
      float4 q2 = *(const float4*)(xb + (size_t)(c0 + 2) * L_N);
      float4 q3 = *(const float4*)(xb + (size_t)(c0 + 3) * L_N);
      float e0[4] = {q0.x, q0.y, q0.z, q0.w};
      float e1[4] = {q1.x, q1.y, q1.z, q1.w};
      float e2[4] = {q2.x, q2.y, q2.z, q2.w};
      float e3[4] = {q3.x, q3.y, q3.z, q3.w};
#pragma unroll
      for (int r = 0; r < 4; ++r) {
        unsigned u0 = cvt_pk_bf16(e0[r], e1[r]);
        unsigned u1 = cvt_pk_bf16(e2[r], e3[r]);
        *(uint2*)&xs[lgrp * 4 + r][c0] = make_uint2(u0, u1);
      }
    }
  }
  __syncthreads();

  // ---- V (values) + Hpre GEMMs, shared A-fragments ----
  f32x4 zero4 = {0.f, 0.f, 0.f, 0.f};
  f32x4 accv[4][2];   // fp32, held through GEMM2 (NO bf16 packing — R4 bug class)
  f32x4 acch[4];
#pragma unroll
  for (int mt = 0; mt < 4; ++mt) {
#pragma unroll
    for (int nt = 0; nt < 2; ++nt) accv[mt][nt] = zero4;
    acch[mt] = zero4;
  }

  for (int k0 = 0; k0 < C_N; k0 += 32) {
    int kb = k0 >> 5;
    bf16x8 af[4];
#pragma unroll
    for (int mt = 0; mt < 4; ++mt)
      af[mt] = *(const bf16x8*)&xs[mt * 16 + lr][k0 + lg * 8];
#pragma unroll
    for (int nt = 0; nt < 2; ++nt) {
      const bf16x8 bf = *(const bf16x8*)&wv[(((wave * 2 + nt) * 8 + kb) * 64 + lane) * 8];
#pragma unroll
      for (int mt = 0; mt < 4; ++mt)
        accv[mt][nt] = __builtin_amdgcn_mfma_f32_16x16x32_bf16(af[mt], bf, accv[mt][nt], 0, 0, 0);
    }
    {
      const bf16x8 bf = *(const bf16x8*)&wt[((wave * 8 + kb) * 64 + lane) * 8];
#pragma unroll
      for (int mt = 0; mt < 4; ++mt)
        acch[mt] = __builtin_amdgcn_mfma_f32_16x16x32_bf16(af[mt], bf, acch[mt], 0, 0, 0);
    }
  }
  __builtin_amdgcn_sched_barrier(0);   // fence: no epilogue code moves into MFMA tail

  // ---- h epilogue: relu + BN affine, write bf16 to LDS [l][a] ----
#pragma unroll
  for (int mt = 0; mt < 4; ++mt) {
#pragma unroll
    for (int r = 0; r < 4; ++r) {
      float hv = acch[mt][r] + hb;
      hv = fmaxf(hv, 0.f) * g + be;
      hs[mt * 16 + lg * 4 + r][ai] = f2bf(hv);
    }
  }
  __syncthreads();

  // ---- S (scores) GEMM: K = A_N ----
  f32x4 accs[4][2];
#pragma unroll
  for (int mt = 0; mt < 4; ++mt)
#pragma unroll
    for (int nt = 0; nt < 2; ++nt) accs[mt][nt] = zero4;

  for (int k0 = 0; k0 < A_N; k0 += 32) {
    int kb = k0 >> 5;
    bf16x8 af[4];
#pragma unroll
    for (int mt = 0; mt < 4; ++mt)
      af[mt] = *(const bf16x8*)&hs[mt * 16 + lr][k0 + lg * 8];
#pragma unroll
    for (int nt = 0; nt < 2; ++nt) {
      const bf16x8 bf = *(const bf16x8*)&wc[(((wave * 2 + nt) * 4 + kb) * 64 + lane) * 8];
#pragma unroll
      for (int mt = 0; mt < 4; ++mt)
        accs[mt][nt] = __builtin_amdgcn_mfma_f32_16x16x32_bf16(af[mt], bf, accs[mt][nt], 0, 0, 0);
    }
  }
  __builtin_amdgcn_sched_barrier(0);

  // ---- per-tile online-softmax partials ----
  bool fullvalid = (float)(l0 + LT - 1) < vlen;

#pragma unroll
  for (int nt = 0; nt < 2; ++nt) {
    int c = wave * 32 + nt * 16 + lr;
    float bc = bc2[nt];
    float bv = bv2[nt];
    float m = -FLT_MAX, ss = 0.f, sv = 0.f, svv = 0.f;
    if (fullvalid) {
#pragma unroll
      for (int mt = 0; mt < 4; ++mt)
#pragma unroll
        for (int r = 0; r < 4; ++r) m = fmaxf(m, accs[mt][nt][r]);
      m = fmaxf(m, __shfl_xor(m, 16));
      m = fmaxf(m, __shfl_xor(m, 32));
#pragma unroll
      for (int mt = 0; mt < 4; ++mt) {
#pragma unroll
        for (int r = 0; r < 4; ++r) {
          float p = __expf(accs[mt][nt][r] - m);
          float v = accv[mt][nt][r] + bv;      // fp32 values, no round-trip
          ss += p; sv += p * v; svv += p * v * v;
        }
      }
    } else {
      float lbase = (float)(l0 + lg * 4);
#pragma unroll
      for (int mt = 0; mt < 4; ++mt)
#pragma unroll
        for (int r = 0; r < 4; ++r) {
          bool valid = (lbase + (float)(mt * 16 + r)) < vlen;
          m = fmaxf(m, valid ? accs[mt][nt][r] : -FLT_MAX);
        }
      m = fmaxf(m, __shfl_xor(m, 16));
      m = fmaxf(m, __shfl_xor(m, 32));
#pragma unroll
      for (int mt = 0; mt < 4; ++mt) {
#pragma unroll
        for (int r = 0; r < 4; ++r) {
          bool valid = (lbase + (float)(mt * 16 + r)) < vlen;
          float p = valid ? __expf(accs[mt][nt][r] - m) : 0.f;
          float v = accv[mt][nt][r] + bv;
          ss += p; sv += p * v; svv += p * v * v;
        }
      }
    }
    m += bc;   // shift partial max to true-score scale (bc cancels inside exp)
    ss += __shfl_xor(ss, 16); ss += __shfl_xor(ss, 32);
    sv += __shfl_xor(sv, 16); sv += __shfl_xor(sv, 32);
    svv += __shfl_xor(svv, 16); svv += __shfl_xor(svv, 32);
    if (lg == 0) {
      partial[(size_t)((b * NTILES + tile) * C_N) + c] = make_float4(m, ss, sv, svv);
    }
  }
}

// ---------------- K4: merge partials, emit amean/astd ----------------
__global__ __launch_bounds__(64)
void k4_combine(const float4* __restrict__ partial, float* __restrict__ out) {
  int blk = blockIdx.x;           // b*256 + c
  int b = blk >> 8, c = blk & 255;
  int lane = threadIdx.x;
  float m = -FLT_MAX, s = 0.f, sv = 0.f, svv = 0.f;
  for (int t = lane; t < NTILES; t += 64) {
    float4 q = partial[(size_t)((b * NTILES + t) * C_N) + c];
    float M = fmaxf(m, q.x);
    float e1 = __expf(m - M), e2 = __expf(q.x - M);
    s = s * e1 + q.y * e2;
    sv = sv * e1 + q.z * e2;
    svv = svv * e1 + q.w * e2;
    m = M;
  }
#pragma unroll
  for (int off = 32; off; off >>= 1) {
    float m2 = __shfl_xor(m, off), s2 = __shfl_xor(s, off);
    float sv2 = __shfl_xor(sv, off), svv2 = __shfl_xor(svv, off);
    float M = fmaxf(m, m2);
    float e1 = __expf(m - M), e2 = __expf(m2 - M);
    s = s * e1 + s2 * e2;
    sv = sv * e1 + sv2 * e2;
    svv = svv * e1 + svv2 * e2;
    m = M;
  }
  if (lane == 0) {
    float amean = sv / s;
    float avar = svv / s - amean * amean;
    out[b * 512 + c] = amean;
    out[b * 512 + 256 + c] = sqrtf(fmaxf(avar, 1e-12f));
  }
}

extern "C" void kernel_launch(void* const* d_in, const int* in_sizes, int n_in,
                              void* d_out, int out_size, void* d_ws, size_t ws_size,
                              hipStream_t stream) {
  const float* x        = (const float*)d_in[0];
  const float* lengths  = (const float*)d_in[1];
  const float* w_val    = (const float*)d_in[2];
  const float* b_val    = (const float*)d_in[3];
  const float* w_tdnn   = (const float*)d_in[4];
  const float* b_tdnn   = (const float*)d_in[5];
  const float* bn_gamma = (const float*)d_in[6];
  const float* bn_beta  = (const float*)d_in[7];
  const float* w_conv   = (const float*)d_in[8];
  const float* b_conv   = (const float*)d_in[9];
  float* out = (float*)d_out;

  char* ws = (char*)d_ws;
  float* gmean     = (float*)(ws + 0);            // 8 KB
  float* gstd      = (float*)(ws + 8 * 1024);     // 8 KB
  float* bias_val  = (float*)(ws + 16 * 1024);    // 8 KB
  float* hbias     = (float*)(ws + 24 * 1024);    // 4 KB
  short* wv        = (short*)(ws + 32 * 1024);    // 128 KB  packed [16cb][8kb][64][8]
  short* wt        = (short*)(ws + 160 * 1024);   // 64 KB   packed [8cb][8kb][64][8]
  short* wc        = (short*)(ws + 224 * 1024);   // 64 KB   packed [16cb][4kb][64][8]
  float4* partial  = (float4*)(ws + 512 * 1024);  // 4 MB    [8][128][256] float4

  kA_stats_convert<<<dim3(2304), dim3(128), 0, stream>>>(x, lengths, w_val, w_tdnn, w_conv,
                                                         gmean, gstd, wv, wt, wc);
  kB_bias<<<dim3(768), dim3(256), 0, stream>>>(w_val, b_val, w_tdnn, b_tdnn,
                                               gmean, gstd, bias_val, hbias);
  k3_main8w<<<dim3(B_N * NTILES), dim3(512), 0, stream>>>(x, lengths, wv, wt, wc,
                                                          bias_val, hbias, bn_gamma, bn_beta,
                                                          b_conv, partial);
  k4_combine<<<dim3(B_N * C_N), dim3(64), 0, stream>>>(partial, out);
}

// Round 17
// 47.617 us; speedup vs baseline: 2.0654x; 1.0013x over previous
//
#include <hip/hip_runtime.h>
#include <float.h>
#include <math.h>

#define B_N 8
#define C_N 256
#define L_N 8192
#define A_N 128
#define LT 64
#define NTILES (L_N / LT)   // 128 tiles per batch

typedef short bf16x8 __attribute__((ext_vector_type(8)));
typedef float f32x4 __attribute__((ext_vector_type(4)));

__device__ __forceinline__ short f2bf(float f) {
  union { float f; unsigned u; } v; v.f = f;
  unsigned r = v.u + 0x7fffu + ((v.u >> 16) & 1u);
  return (short)(r >> 16);
}

__device__ __forceinline__ unsigned cvt_pk_bf16(float lo, float hi) {
  unsigned r;
  asm("v_cvt_pk_bf16_f32 %0, %1, %2" : "=v"(r) : "v"(lo), "v"(hi));
  return r;
}

// ---------------- Kernel A: stats (blocks 0..2047) + weight convert (blocks 2048..2303) ----------
__global__ __launch_bounds__(128)
void kA_stats_convert(const float* __restrict__ x, const float* __restrict__ lengths,
                      const float* __restrict__ w_val, const float* __restrict__ w_tdnn,
                      const float* __restrict__ w_conv,
                      float* __restrict__ gmean, float* __restrict__ gstd,
                      short* __restrict__ wv, short* __restrict__ wt, short* __restrict__ wc) {
  if (blockIdx.x < 2048) {
    __shared__ float sm[2][3];
    int blk = blockIdx.x;              // b*256 + c
    int b = blk >> 8;
    int wave = threadIdx.x >> 6;
    int lane = threadIdx.x & 63;
    float vlen = lengths[b] * (float)L_N;
    const float4* row = (const float4*)(x + (size_t)blk * L_N + wave * (L_N / 2));
    float s = 0.f, s2 = 0.f, cnt = 0.f;
    if (wave == 0) {
#pragma unroll 4
      for (int i = lane; i < 1024; i += 64) {
        float4 q = row[i];
        s += q.x + q.y + q.z + q.w;
        s2 += q.x * q.x + q.y * q.y + q.z * q.z + q.w * q.w;
      }
      cnt = 64.f;
    } else {
      for (int i = lane; i < 1024; i += 64) {
        int l = 4096 + i * 4;
        if ((float)l >= vlen) break;
        float4 q = row[i];
        if ((float)(l + 3) < vlen) {
          s += q.x + q.y + q.z + q.w;
          s2 += q.x * q.x + q.y * q.y + q.z * q.z + q.w * q.w;
          cnt += 4.f;
        } else {
          float e[4] = {q.x, q.y, q.z, q.w};
#pragma unroll
          for (int j = 0; j < 4; ++j) {
            if ((float)(l + j) < vlen) { float t = e[j]; s += t; s2 += t * t; cnt += 1.f; }
          }
        }
      }
    }
#pragma unroll
    for (int off = 32; off; off >>= 1) {
      s += __shfl_xor(s, off); s2 += __shfl_xor(s2, off); cnt += __shfl_xor(cnt, off);
    }
    if (lane == 0) { sm[wave][0] = s; sm[wave][1] = s2; sm[wave][2] = cnt; }
    __syncthreads();
    if (threadIdx.x == 0) {
      float S = sm[0][0] + sm[1][0];
      float S2 = sm[0][1] + sm[1][1];
      float CNT = sm[0][2] + sm[1][2];
      float mean = S / CNT;
      float var = S2 / CNT - mean * mean;
      gmean[blk] = mean;
      gstd[blk] = sqrtf(fmaxf(var, 1e-12f));
    }
  } else {
    int unit = (blockIdx.x - 2048) * 2 + (threadIdx.x >> 6);   // 0..511
    int lane = threadIdx.x & 63;
    int t = unit * 64 + lane;            // 0..32767
    const float* src;
    short* dst;
    int p, c, k, rowlen;
    if (t < 16384) {                     // wv: [16 colblk][8 kblk]
      p = t * 4;
      int j0 = p & 7, lane_ = (p >> 3) & 63, bi = p >> 9;
      int kblk = bi & 7, colblk = bi >> 3;
      c = colblk * 16 + (lane_ & 15);
      k = kblk * 32 + (lane_ >> 4) * 8 + j0;
      src = w_val; dst = wv; rowlen = 768;
    } else if (t < 24576) {              // wt: [8 colblk][8 kblk]
      p = (t - 16384) * 4;
      int j0 = p & 7, lane_ = (p >> 3) & 63, bi = p >> 9;
      int kblk = bi & 7, colblk = bi >> 3;
      c = colblk * 16 + (lane_ & 15);
      k = kblk * 32 + (lane_ >> 4) * 8 + j0;
      src = w_tdnn; dst = wt; rowlen = 768;
    } else {                             // wc: [16 colblk][4 kblk]
      p = (t - 24576) * 4;
      int j0 = p & 7, lane_ = (p >> 3) & 63, bi = p >> 9;
      int kblk = bi & 3, colblk = bi >> 2;
      c = colblk * 16 + (lane_ & 15);
      k = kblk * 32 + (lane_ >> 4) * 8 + j0;
      src = w_conv; dst = wc; rowlen = 128;
    }
    float4 q = *(const float4*)(src + (size_t)c * rowlen + k);
    short4 o = make_short4(f2bf(q.x), f2bf(q.y), f2bf(q.z), f2bf(q.w));
    *(short4*)(dst + p) = o;
  }
}

// ---------------- Kernel B: fp32 bias GEMVs (needs stats) ----------------
__global__ __launch_bounds__(256)
void kB_bias(const float* __restrict__ w_val, const float* __restrict__ b_val,
             const float* __restrict__ w_tdnn, const float* __restrict__ b_tdnn,
             const float* __restrict__ gmean, const float* __restrict__ gstd,
             float* __restrict__ bias_val, float* __restrict__ hbias) {
  int unit = blockIdx.x * 4 + (threadIdx.x >> 6);   // 0..3071
  int lane = threadIdx.x & 63;
  if (unit < 2048) {                      // bias_val[b][c]
    int b = unit >> 8, c = unit & 255;
    const float* wr = w_val + c * 768;
    const float* gm = gmean + b * 256;
    const float* gs = gstd + b * 256;
    float s = 0.f;
    for (int j = lane; j < 256; j += 64)
      s += gm[j] * wr[256 + j] + gs[j] * wr[512 + j];
#pragma unroll
    for (int off = 32; off; off >>= 1) s += __shfl_xor(s, off);
    if (lane == 0) bias_val[b * 256 + c] = s + b_val[c];
  } else {                                // hbias[b][a]
    int t = unit - 2048;
    int b = t >> 7, a = t & 127;
    const float* wr = w_tdnn + a * 768;
    const float* gm = gmean + b * 256;
    const float* gs = gstd + b * 256;
    float s = 0.f;
    for (int j = lane; j < 256; j += 64)
      s += gm[j] * wr[256 + j] + gs[j] * wr[512 + j];
#pragma unroll
    for (int off = 32; off; off >>= 1) s += __shfl_xor(s, off);
    if (lane == 0) hbias[b * 128 + a] = s + b_tdnn[a];
  }
}

// ---------------- K3 (R13 proven): verified 8-wave + invalid-tile early exit ----------------
__global__ __launch_bounds__(512, 4)
void k3_main8w(const float* __restrict__ x, const float* __restrict__ lengths,
               const short* __restrict__ wv, const short* __restrict__ wt,
               const short* __restrict__ wc,
               const float* __restrict__ bias_val, const float* __restrict__ hbias,
               const float* __restrict__ bn_gamma, const float* __restrict__ bn_beta,
               const float* __restrict__ b_conv,
               float4* __restrict__ partial) {
  __shared__ short xs[LT][C_N + 8];   // x tile [l][c'] bf16
  __shared__ short hs[LT][A_N + 8];   // h tile [l][a] bf16

  int blk = blockIdx.x;
  int b = blk >> 7;
  int tile = blk & 127;
  int l0 = tile * LT;
  int tid = threadIdx.x;
  int wave = tid >> 6;     // 0..7
  int lane = tid & 63;
  int lr = lane & 15;
  int lg = lane >> 4;

  float vlen = lengths[b] * (float)L_N;

  // ---- fully-invalid tile: partials are exactly (-inf,0,0,0); skip all compute ----
  if ((float)l0 >= vlen) {
    if (lg == 0) {
#pragma unroll
      for (int nt = 0; nt < 2; ++nt) {
        int c = wave * 32 + nt * 16 + lr;
        partial[(size_t)((b * NTILES + tile) * C_N) + c] = make_float4(-FLT_MAX, 0.f, 0.f, 0.f);
      }
    }
    return;
  }

  // ---- prefetch per-thread epilogue constants ----
  int ai = wave * 16 + lr;               // h col this thread handles
  float hb = hbias[b * A_N + ai];
  float g  = bn_gamma[ai];
  float be = bn_beta[ai];
  float bc2[2], bv2[2];
#pragma unroll
  for (int nt = 0; nt < 2; ++nt) {
    int c = wave * 32 + nt * 16 + lr;
    bc2[nt] = b_conv[c];
    bv2[nt] = bias_val[b * C_N + c];
  }

  // ---- stage x tile: global [c'][l] fp32 -> LDS [l][c'] bf16 ----
  {
    int lgrp = tid & 15;
    int crow = tid >> 4;                 // 0..31
    const float* xb = x + (size_t)b * C_N * L_N + l0 + lgrp * 4;
#pragma unroll
    for (int i = 0; i < 2; ++i) {
      int c0 = (i * 32 + crow) * 4;
      float4 q0 = *(const float4*)(xb + (size_t)(c0 + 0) * L_N);
      float4 q1 = *(const float4*)(xb + (size_t)(c0 + 1) * L_N);
      float4 q2 = *(const float4*)(xb + (size_t)(c0 + 2) * L_N);
      float4 q3 = *(const float4*)(xb + (size_t)(c0 + 3) * L_N);
      float e0[4] = {q0.x, q0.y, q0.z, q0.w};
      float e1[4] = {q1.x, q1.y, q1.z, q1.w};
      float e2[4] = {q2.x, q2.y, q2.z, q2.w};
      float e3[4] = {q3.x, q3.y, q3.z, q3.w};
#pragma unroll
      for (int r = 0; r < 4; ++r) {
        unsigned u0 = cvt_pk_bf16(e0[r], e1[r]);
        unsigned u1 = cvt_pk_bf16(e2[r], e3[r]);
        *(uint2*)&xs[lgrp * 4 + r][c0] = make_uint2(u0, u1);
      }
    }
  }
  __syncthreads();

  // ---- V (values) + Hpre GEMMs, shared A-fragments ----
  f32x4 zero4 = {0.f, 0.f, 0.f, 0.f};
  f32x4 accv[4][2];   // fp32, held through GEMM2 (NO bf16 packing — R4 bug class)
  f32x4 acch[4];
#pragma unroll
  for (int mt = 0; mt < 4; ++mt) {
#pragma unroll
    for (int nt = 0; nt < 2; ++nt) accv[mt][nt] = zero4;
    acch[mt] = zero4;
  }

  for (int k0 = 0; k0 < C_N; k0 += 32) {
    int kb = k0 >> 5;
    bf16x8 af[4];
#pragma unroll
    for (int mt = 0; mt < 4; ++mt)
      af[mt] = *(const bf16x8*)&xs[mt * 16 + lr][k0 + lg * 8];
#pragma unroll
    for (int nt = 0; nt < 2; ++nt) {
      const bf16x8 bf = *(const bf16x8*)&wv[(((wave * 2 + nt) * 8 + kb) * 64 + lane) * 8];
#pragma unroll
      for (int mt = 0; mt < 4; ++mt)
        accv[mt][nt] = __builtin_amdgcn_mfma_f32_16x16x32_bf16(af[mt], bf, accv[mt][nt], 0, 0, 0);
    }
    {
      const bf16x8 bf = *(const bf16x8*)&wt[((wave * 8 + kb) * 64 + lane) * 8];
#pragma unroll
      for (int mt = 0; mt < 4; ++mt)
        acch[mt] = __builtin_amdgcn_mfma_f32_16x16x32_bf16(af[mt], bf, acch[mt], 0, 0, 0);
    }
  }
  __builtin_amdgcn_sched_barrier(0);   // fence: no epilogue code moves into MFMA tail

  // ---- h epilogue: relu + BN affine, write bf16 to LDS [l][a] ----
#pragma unroll
  for (int mt = 0; mt < 4; ++mt) {
#pragma unroll
    for (int r = 0; r < 4; ++r) {
      float hv = acch[mt][r] + hb;
      hv = fmaxf(hv, 0.f) * g + be;
      hs[mt * 16 + lg * 4 + r][ai] = f2bf(hv);
    }
  }
  __syncthreads();

  // ---- S (scores) GEMM: K = A_N ----
  f32x4 accs[4][2];
#pragma unroll
  for (int mt = 0; mt < 4; ++mt)
#pragma unroll
    for (int nt = 0; nt < 2; ++nt) accs[mt][nt] = zero4;

  for (int k0 = 0; k0 < A_N; k0 += 32) {
    int kb = k0 >> 5;
    bf16x8 af[4];
#pragma unroll
    for (int mt = 0; mt < 4; ++mt)
      af[mt] = *(const bf16x8*)&hs[mt * 16 + lr][k0 + lg * 8];
#pragma unroll
    for (int nt = 0; nt < 2; ++nt) {
      const bf16x8 bf = *(const bf16x8*)&wc[(((wave * 2 + nt) * 4 + kb) * 64 + lane) * 8];
#pragma unroll
      for (int mt = 0; mt < 4; ++mt)
        accs[mt][nt] = __builtin_amdgcn_mfma_f32_16x16x32_bf16(af[mt], bf, accs[mt][nt], 0, 0, 0);
    }
  }
  __builtin_amdgcn_sched_barrier(0);

  // ---- per-tile online-softmax partials ----
  bool fullvalid = (float)(l0 + LT - 1) < vlen;

#pragma unroll
  for (int nt = 0; nt < 2; ++nt) {
    int c = wave * 32 + nt * 16 + lr;
    float bc = bc2[nt];
    float bv = bv2[nt];
    float m = -FLT_MAX, ss = 0.f, sv = 0.f, svv = 0.f;
    if (fullvalid) {
#pragma unroll
      for (int mt = 0; mt < 4; ++mt)
#pragma unroll
        for (int r = 0; r < 4; ++r) m = fmaxf(m, accs[mt][nt][r]);
      m = fmaxf(m, __shfl_xor(m, 16));
      m = fmaxf(m, __shfl_xor(m, 32));
#pragma unroll
      for (int mt = 0; mt < 4; ++mt) {
#pragma unroll
        for (int r = 0; r < 4; ++r) {
          float p = __expf(accs[mt][nt][r] - m);
          float v = accv[mt][nt][r] + bv;      // fp32 values, no round-trip
          ss += p; sv += p * v; svv += p * v * v;
        }
      }
    } else {
      float lbase = (float)(l0 + lg * 4);
#pragma unroll
      for (int mt = 0; mt < 4; ++mt)
#pragma unroll
        for (int r = 0; r < 4; ++r) {
          bool valid = (lbase + (float)(mt * 16 + r)) < vlen;
          m = fmaxf(m, valid ? accs[mt][nt][r] : -FLT_MAX);
        }
      m = fmaxf(m, __shfl_xor(m, 16));
      m = fmaxf(m, __shfl_xor(m, 32));
#pragma unroll
      for (int mt = 0; mt < 4; ++mt) {
#pragma unroll
        for (int r = 0; r < 4; ++r) {
          bool valid = (lbase + (float)(mt * 16 + r)) < vlen;
          float p = valid ? __expf(accs[mt][nt][r] - m) : 0.f;
          float v = accv[mt][nt][r] + bv;
          ss += p; sv += p * v; svv += p * v * v;
        }
      }
    }
    m += bc;   // shift partial max to true-score scale (bc cancels inside exp)
    ss += __shfl_xor(ss, 16); ss += __shfl_xor(ss, 32);
    sv += __shfl_xor(sv, 16); sv += __shfl_xor(sv, 32);
    svv += __shfl_xor(svv, 16); svv += __shfl_xor(svv, 32);
    if (lg == 0) {
      partial[(size_t)((b * NTILES + tile) * C_N) + c] = make_float4(m, ss, sv, svv);
    }
  }
}

// ---------------- K4: merge partials, emit amean/astd ----------------
__global__ __launch_bounds__(64)
void k4_combine(const float4* __restrict__ partial, float* __restrict__ out) {
  int blk = blockIdx.x;           // b*256 + c
  int b = blk >> 8, c = blk & 255;
  int lane = threadIdx.x;
  float m = -FLT_MAX, s = 0.f, sv = 0.f, svv = 0.f;
  for (int t = lane; t < NTILES; t += 64) {
    float4 q = partial[(size_t)((b * NTILES + t) * C_N) + c];
    float M = fmaxf(m, q.x);
    float e1 = __expf(m - M), e2 = __expf(q.x - M);
    s = s * e1 + q.y * e2;
    sv = sv * e1 + q.z * e2;
    svv = svv * e1 + q.w * e2;
    m = M;
  }
#pragma unroll
  for (int off = 32; off; off >>= 1) {
    float m2 = __shfl_xor(m, off), s2 = __shfl_xor(s, off);
    float sv2 = __shfl_xor(sv, off), svv2 = __shfl_xor(svv, off);
    float M = fmaxf(m, m2);
    float e1 = __expf(m - M), e2 = __expf(m2 - M);
    s = s * e1 + s2 * e2;
    sv = sv * e1 + sv2 * e2;
    svv = svv * e1 + svv2 * e2;
    m = M;
  }
  if (lane == 0) {
    float amean = sv / s;
    float avar = svv / s - amean * amean;
    out[b * 512 + c] = amean;
    out[b * 512 + 256 + c] = sqrtf(fmaxf(avar, 1e-12f));
  }
}

extern "C" void kernel_launch(void* const* d_in, const int* in_sizes, int n_in,
                              void* d_out, int out_size, void* d_ws, size_t ws_size,
                              hipStream_t stream) {
  const float* x        = (const float*)d_in[0];
  const float* lengths  = (const float*)d_in[1];
  const float* w_val    = (const float*)d_in[2];
  const float* b_val    = (const float*)d_in[3];
  const float* w_tdnn   = (const float*)d_in[4];
  const float* b_tdnn   = (const float*)d_in[5];
  const float* bn_gamma = (const float*)d_in[6];
  const float* bn_beta  = (const float*)d_in[7];
  const float* w_conv   = (const float*)d_in[8];
  const float* b_conv   = (const float*)d_in[9];
  float* out = (float*)d_out;

  char* ws = (char*)d_ws;
  float* gmean     = (float*)(ws + 0);            // 8 KB
  float* gstd      = (float*)(ws + 8 * 1024);     // 8 KB
  float* bias_val  = (float*)(ws + 16 * 1024);    // 8 KB
  float* hbias     = (float*)(ws + 24 * 1024);    // 4 KB
  short* wv        = (short*)(ws + 32 * 1024);    // 128 KB  packed [16cb][8kb][64][8]
  short* wt        = (short*)(ws + 160 * 1024);   // 64 KB   packed [8cb][8kb][64][8]
  short* wc        = (short*)(ws + 224 * 1024);   // 64 KB   packed [16cb][4kb][64][8]
  float4* partial  = (float4*)(ws + 512 * 1024);  // 4 MB    [8][128][256] float4

  kA_stats_convert<<<dim3(2304), dim3(128), 0, stream>>>(x, lengths, w_val, w_tdnn, w_conv,
                                                         gmean, gstd, wv, wt, wc);
  kB_bias<<<dim3(768), dim3(256), 0, stream>>>(w_val, b_val, w_tdnn, b_tdnn,
                                               gmean, gstd, bias_val, hbias);
  k3_main8w<<<dim3(B_N * NTILES), dim3(512), 0, stream>>>(x, lengths, wv, wt, wc,
                                                          bias_val, hbias, bn_gamma, bn_beta,
                                                          b_conv, partial);
  k4_combine<<<dim3(B_N * C_N), dim3(64), 0, stream>>>(partial, out);
}